// Round 11
// baseline (108.195 us; speedup 1.0000x reference)
//
#include <hip/hip_runtime.h>
#include <hip/hip_bf16.h>
#include <stdint.h>

typedef __bf16 bf16x8 __attribute__((ext_vector_type(8)));
typedef float  f32x4  __attribute__((ext_vector_type(4)));

#define B_   2
#define T_   2048
#define H_   16
#define DH_  64
#define DM_  1024
#define BH_  (B_*H_)   // 32
#define M_   (B_*T_)   // 4096

#define QSCALE 0.18033688f   // 1/sqrt(64) * log2(e), folded into Q
#define FIXED_M 8.0f         // static softmax max (exp2 domain)

// ---- async global->LDS, 16B per lane; LDS dest must be wave-uniform base ----
static __device__ __forceinline__ void gload_lds16(const void* g, void* lds) {
  __builtin_amdgcn_global_load_lds(
      (const __attribute__((address_space(1))) void*)(uintptr_t)g,
      (__attribute__((address_space(3))) void*)(uint32_t)(uintptr_t)lds,
      16, 0, 0);
}

// ---------------- fused prep: cvt x + transpose both weights ----------------
// blocks 0..4095: x f32->bf16 (float4 vectorized)
// blocks 4096..7167: w_qkv [1024][3072] -> wqkvT [3072][1024] bf16
// blocks 7168..8191: w_out [1024][1024] -> woutT bf16
__global__ void k_prep(const float* __restrict__ x, const float* __restrict__ wqkv,
                       const float* __restrict__ wout, __hip_bfloat16* __restrict__ xb,
                       __hip_bfloat16* __restrict__ wqkvT, __hip_bfloat16* __restrict__ woutT) {
  __shared__ float tile[32][33];
  const int bid = blockIdx.x, tid = threadIdx.x;
  if (bid < 4096) {
    int i = bid * 256 + tid;                       // 1M float4 = all of x
    float4 v = reinterpret_cast<const float4*>(x)[i];
    alignas(8) __hip_bfloat16 t[4] = {__float2bfloat16(v.x), __float2bfloat16(v.y),
                                      __float2bfloat16(v.z), __float2bfloat16(v.w)};
    reinterpret_cast<uint2*>(xb)[i] = *reinterpret_cast<const uint2*>(t);
    return;
  }
  const float* in; __hip_bfloat16* out; int K, N, n0, k0;
  if (bid < 7168) {
    int t = bid - 4096; in = wqkv; out = wqkvT; K = 1024; N = 3072;
    n0 = (t % 96) * 32; k0 = (t / 96) * 32;
  } else {
    int t = bid - 7168; in = wout; out = woutT; K = 1024; N = 1024;
    n0 = (t % 32) * 32; k0 = (t / 32) * 32;
  }
  int kl = tid >> 3, n4 = (tid & 7) * 4;
  float4 v = *reinterpret_cast<const float4*>(in + (size_t)(k0 + kl) * N + n0 + n4);
  tile[kl][n4 + 0] = v.x; tile[kl][n4 + 1] = v.y; tile[kl][n4 + 2] = v.z; tile[kl][n4 + 3] = v.w;
  __syncthreads();
  int nl = tid >> 3, k4 = (tid & 7) * 4;
  alignas(8) __hip_bfloat16 t[4];
  #pragma unroll
  for (int j = 0; j < 4; ++j) t[j] = __float2bfloat16(tile[k4 + j][nl]);
  *reinterpret_cast<uint2*>(out + (size_t)(n0 + nl) * K + k0 + k4) = *reinterpret_cast<const uint2*>(t);
}

// ---- pipelined bf16 GEMM core (B^T input), BK=32, 4 waves, 3-slot ring ----
template<int BM, int BN, int FM, int FN>
static __device__ __forceinline__ void gemm_core_pipe(
    const __hip_bfloat16* __restrict__ A, const __hip_bfloat16* __restrict__ BT,
    int K, int brow, int bcol, __hip_bfloat16* As, __hip_bfloat16* Bs,
    f32x4 acc[FM][FN]) {
  constexpr int WGN = BN / (16 * FN);
  constexpr int LOADS = BM / 64 + BN / 64;       // gloads per wave per stage
  constexpr int ASLOT = BM * 32, BSLOT = BN * 32;
  const int tid = threadIdx.x, wave = tid >> 6, lane = tid & 63;
  const int wr = wave / WGN, wc = wave % WGN;
  const int llo = lane & 15, lhi = lane >> 4;
  const int nk = K / 32;
  auto stage = [&](int ks, int slot) {
    #pragma unroll
    for (int c = wave; c < BM / 16; c += 4)
      gload_lds16(A + (size_t)(brow + c * 16 + (lane >> 2)) * K + ks * 32 + (lane & 3) * 8,
                  As + slot * ASLOT + c * 512);
    #pragma unroll
    for (int c = wave; c < BN / 16; c += 4)
      gload_lds16(BT + (size_t)(bcol + c * 16 + (lane >> 2)) * K + ks * 32 + (lane & 3) * 8,
                  Bs + slot * BSLOT + c * 512);
  };
  stage(0, 0);
  stage(1, 1);
  for (int ks = 0; ks < nk; ++ks) {
    if constexpr (LOADS == 4)      asm volatile("s_waitcnt vmcnt(4)" ::: "memory");
    else if constexpr (LOADS == 3) asm volatile("s_waitcnt vmcnt(3)" ::: "memory");
    else                           asm volatile("s_waitcnt vmcnt(0)" ::: "memory");
    __builtin_amdgcn_sched_barrier(0);
    __builtin_amdgcn_s_barrier();
    __builtin_amdgcn_sched_barrier(0);
    const int s2 = (ks + 2 < nk) ? ks + 2 : nk - 1;  // clamped redundant tail
    stage(s2, (ks + 2) % 3);
    const __hip_bfloat16* Asl = As + (ks % 3) * ASLOT;
    const __hip_bfloat16* Bsl = Bs + (ks % 3) * BSLOT;
    bf16x8 a[FM], b[FN];
    #pragma unroll
    for (int i = 0; i < FM; ++i)
      a[i] = *reinterpret_cast<const bf16x8*>(Asl + (wr * FM * 16 + i * 16 + llo) * 32 + lhi * 8);
    #pragma unroll
    for (int j = 0; j < FN; ++j)
      b[j] = *reinterpret_cast<const bf16x8*>(Bsl + (wc * FN * 16 + j * 16 + llo) * 32 + lhi * 8);
    __builtin_amdgcn_s_setprio(1);
    #pragma unroll
    for (int i = 0; i < FM; ++i)
      #pragma unroll
      for (int j = 0; j < FN; ++j)
        acc[i][j] = __builtin_amdgcn_mfma_f32_16x16x32_bf16(a[i], b[j], acc[i][j], 0, 0, 0);
    __builtin_amdgcn_s_setprio(0);
  }
  asm volatile("s_waitcnt vmcnt(0)" ::: "memory");
}

// GEMM1: qkv = xb @ w_qkv ; Q (pre-scaled) / K as [bh][t][dh]; V directly
// transposed to [bh][dh][t] (4 consecutive t per lane -> packed 8B store).
__global__ __launch_bounds__(256) void k_gemm_qkv(
    const __hip_bfloat16* __restrict__ A, const __hip_bfloat16* __restrict__ BT,
    __hip_bfloat16* __restrict__ q_ws, __hip_bfloat16* __restrict__ k_ws,
    __hip_bfloat16* __restrict__ vT) {
  alignas(16) __shared__ __hip_bfloat16 As[3 * 128 * 32];
  alignas(16) __shared__ __hip_bfloat16 Bs[3 * 128 * 32];
  f32x4 acc[4][4] = {};
  const int brow = blockIdx.y * 128, bcol = blockIdx.x * 128;
  gemm_core_pipe<128, 128, 4, 4>(A, BT, DM_, brow, bcol, As, Bs, acc);
  const int tid = threadIdx.x, wave = tid >> 6, lane = tid & 63;
  const int wr = wave >> 1, wc = wave & 1;
  const int llo = lane & 15, lhi = lane >> 4;
  #pragma unroll
  for (int i = 0; i < 4; ++i) {
    const int tbase = brow + wr * 64 + i * 16 + lhi * 4;  // 4 consecutive t
    const int b = tbase >> 11, t = tbase & 2047;
    #pragma unroll
    for (int j = 0; j < 4; ++j) {
      int n = bcol + wc * 64 + j * 16 + llo;
      int part = n >> 10, rem = n & 1023, hh = rem >> 6, dh = rem & 63;
      if (part == 2) {
        alignas(8) __hip_bfloat16 tv[4];
        #pragma unroll
        for (int r = 0; r < 4; ++r) tv[r] = __float2bfloat16(acc[i][j][r]);
        *reinterpret_cast<uint2*>(
            vT + (((size_t)(b * H_ + hh)) * DH_ + dh) * T_ + t) =
            *reinterpret_cast<const uint2*>(tv);
      } else {
        float sc = (part == 0) ? QSCALE : 1.0f;   // fold softmax scale into Q
        __hip_bfloat16* dst = (part == 0) ? q_ws : k_ws;
        #pragma unroll
        for (int r = 0; r < 4; ++r)
          dst[(((size_t)(b * H_ + hh)) * T_ + t + r) * DH_ + dh] =
              __float2bfloat16(acc[i][j][r] * sc);
      }
    }
  }
}

// GEMM2: out = y @ w_out (f32 output). 128x64 tile -> 512 blocks (2/CU).
__global__ __launch_bounds__(256) void k_gemm_out(
    const __hip_bfloat16* __restrict__ A, const __hip_bfloat16* __restrict__ BT,
    float* __restrict__ C) {
  alignas(16) __shared__ __hip_bfloat16 As[3 * 128 * 32];
  alignas(16) __shared__ __hip_bfloat16 Bs[3 * 64 * 32];
  f32x4 acc[4][2] = {};
  const int brow = blockIdx.y * 128, bcol = blockIdx.x * 64;
  gemm_core_pipe<128, 64, 4, 2>(A, BT, DM_, brow, bcol, As, Bs, acc);
  const int tid = threadIdx.x, wave = tid >> 6, lane = tid & 63;
  const int wr = wave >> 1, wc = wave & 1;
  const int llo = lane & 15, lhi = lane >> 4;
  #pragma unroll
  for (int i = 0; i < 4; ++i)
    #pragma unroll
    for (int j = 0; j < 2; ++j) {
      int n = bcol + wc * 32 + j * 16 + llo;
      #pragma unroll
      for (int r = 0; r < 4; ++r) {
        int m = brow + wr * 64 + i * 16 + lhi * 4 + r;
        C[(size_t)m * DM_ + n] = acc[i][j][r];
      }
    }
}

// ---------------- flash attention (causal), v10 ----------------
// v6 skeleton (4-slot K/V ring, stage-ahead-2, counted vmcnt(4) + s_barrier,
// static-max softmax, XOR-swizzled K/V) with QBLK=32 per wave: each wave owns
// TWO 16-row fragments from two q-tiles -- f0 = qt0 = 31-2pp-group (high),
// f1 = qt1 = 2pp+group (low); per-wave visits = 33, uniform. Each K/V
// fragment read feeds both f-phases (per-q-row LDS traffic halved, 2x MFMA
// per barrier). All state in named arrays with unroll-only indexing (rule
// #20). f0 overshoot (group1 last iter) handled by masking at it >= qt0;
// f1 guarded wave-uniformly by it <= qt1. Grid (8, BH) = 256 blocks.
__global__ __launch_bounds__(512, 2) void k_attn(
    const __hip_bfloat16* __restrict__ Q, const __hip_bfloat16* __restrict__ Kk,
    const __hip_bfloat16* __restrict__ VT, __hip_bfloat16* __restrict__ Y) {
  alignas(16) __shared__ __hip_bfloat16 Ks[4][64 * 64];
  alignas(16) __shared__ __hip_bfloat16 Vs[4][64 * 64];   // [dh][t'] swizzled
  alignas(16) __shared__ __hip_bfloat16 Ps[8][16 * 64];
  const int pp = blockIdx.x;                 // 0..7
  const int bh = blockIdx.y;
  const int tid = threadIdx.x, wave = tid >> 6, lane = tid & 63;
  const int llo = lane & 15, lhi = lane >> 4;
  const int group = wave >> 2, ws = wave & 3;
  const int qt0 = 31 - 2 * pp - group;       // high q-tile (f0)
  const int qt1 = 2 * pp + group;            // low q-tile (f1)
  const int qb0 = qt0 * 64 + ws * 16;
  const int qb1 = qt1 * 64 + ws * 16;
  const int ntA = 32 - 2 * pp;               // loop length (>= 18)

  const __hip_bfloat16* kb = Kk + (size_t)bh * T_ * DH_;
  const __hip_bfloat16* vb = VT + (size_t)bh * DH_ * T_;

  const int srow = lane >> 3;                // 0..7
  const int schunk = (lane & 7) ^ srow;      // involution XOR
  const int rb = wave * 8;

  bf16x8 aq0[2], aq1[2];
  #pragma unroll
  for (int k0 = 0; k0 < 2; ++k0) {
    aq0[k0] = *reinterpret_cast<const bf16x8*>(
        Q + ((size_t)bh * T_ + qb0 + llo) * DH_ + k0 * 32 + lhi * 8);
    aq1[k0] = *reinterpret_cast<const bf16x8*>(
        Q + ((size_t)bh * T_ + qb1 + llo) * DH_ + k0 * 32 + lhi * 8);
  }

  float l0[4] = {}, l1[4] = {};
  f32x4 o0[4] = {}, o1[4] = {};

  // prologue: stage tiles 0,1 into buffers 0,1 (ntA >= 18)
  gload_lds16(kb + (size_t)(rb + srow) * DH_ + schunk * 8, &Ks[0][rb * 64]);
  gload_lds16(vb + (size_t)(rb + srow) * T_ + schunk * 8, &Vs[0][rb * 64]);
  gload_lds16(kb + (size_t)(64 + rb + srow) * DH_ + schunk * 8, &Ks[1][rb * 64]);
  gload_lds16(vb + (size_t)(rb + srow) * T_ + 64 + schunk * 8, &Vs[1][rb * 64]);

  for (int it = 0; it < ntA; ++it) {
    const int cur = it & 3;
    // stage tile it+2 (clamped tail keeps 2 loads/wave/iter: vmcnt(4) exact)
    {
      const int ts = (it + 2 < ntA) ? (it + 2) : (ntA - 1);
      const int bs = (it + 2) & 3;
      const int tn = ts * 64;
      gload_lds16(kb + (size_t)(tn + rb + srow) * DH_ + schunk * 8, &Ks[bs][rb * 64]);
      gload_lds16(vb + (size_t)(rb + srow) * T_ + tn + schunk * 8, &Vs[bs][rb * 64]);
    }
    asm volatile("s_waitcnt vmcnt(4)" ::: "memory");
    __builtin_amdgcn_sched_barrier(0);
    __builtin_amdgcn_s_barrier();
    __builtin_amdgcn_sched_barrier(0);

    const __hip_bfloat16* ksb = Ks[cur];
    const __hip_bfloat16* vsb = Vs[cur];
    const bool act1 = (it <= qt1);           // wave-uniform

    // ---- QK^T: 8 K-frag reads feed up to 16 MFMA (both q-fragments) ----
    f32x4 s0[4], s1[4];
    __builtin_amdgcn_s_setprio(1);
    #pragma unroll
    for (int jn = 0; jn < 4; ++jn) {
      const __hip_bfloat16* krow = ksb + (jn * 16 + llo) * 64;
      bf16x8 kb0 = *reinterpret_cast<const bf16x8*>(krow + ((lhi ^ (llo & 7)) << 3));
      bf16x8 kb1 = *reinterpret_cast<const bf16x8*>(krow + (((4 + lhi) ^ (llo & 7)) << 3));
      f32x4 z = {};
      z = __builtin_amdgcn_mfma_f32_16x16x32_bf16(aq0[0], kb0, z, 0, 0, 0);
      z = __builtin_amdgcn_mfma_f32_16x16x32_bf16(aq0[1], kb1, z, 0, 0, 0);
      s0[jn] = z;
      if (act1) {
        f32x4 w = {};
        w = __builtin_amdgcn_mfma_f32_16x16x32_bf16(aq1[0], kb0, w, 0, 0, 0);
        w = __builtin_amdgcn_mfma_f32_16x16x32_bf16(aq1[1], kb1, w, 0, 0, 0);
        s1[jn] = w;
      }
    }
    __builtin_amdgcn_s_setprio(0);
    // mask f0 whenever it >= qt0 (diagonal tile, or full overshoot tile)
    if (it >= qt0) {
      #pragma unroll
      for (int jn = 0; jn < 4; ++jn)
        #pragma unroll
        for (int r = 0; r < 4; ++r) {
          int qrow = qb0 + lhi * 4 + r;
          int tcol = it * 64 + jn * 16 + llo;
          if (tcol > qrow) s0[jn][r] = -INFINITY;
        }
    }
    if (act1 && it == qt1) {
      #pragma unroll
      for (int jn = 0; jn < 4; ++jn)
        #pragma unroll
        for (int r = 0; r < 4; ++r) {
          int qrow = qb1 + lhi * 4 + r;
          int tcol = it * 64 + jn * 16 + llo;
          if (tcol > qrow) s1[jn][r] = -INFINITY;
        }
    }
    // static-max softmax in place
    #pragma unroll
    for (int jn = 0; jn < 4; ++jn)
      #pragma unroll
      for (int r = 0; r < 4; ++r) {
        float pv = __builtin_amdgcn_exp2f(s0[jn][r] - FIXED_M);
        s0[jn][r] = pv;
        l0[r] += pv;
      }
    if (act1) {
      #pragma unroll
      for (int jn = 0; jn < 4; ++jn)
        #pragma unroll
        for (int r = 0; r < 4; ++r) {
          float pv = __builtin_amdgcn_exp2f(s1[jn][r] - FIXED_M);
          s1[jn][r] = pv;
          l1[r] += pv;
        }
    }
    // ---- V fragments once into registers (reused by both P phases) ----
    bf16x8 vb0[4], vb1[4];
    #pragma unroll
    for (int jd = 0; jd < 4; ++jd) {
      const __hip_bfloat16* vrow = vsb + (jd * 16 + llo) * 64;
      vb0[jd] = *reinterpret_cast<const bf16x8*>(vrow + ((lhi ^ (llo & 7)) << 3));
      vb1[jd] = *reinterpret_cast<const bf16x8*>(vrow + (((4 + lhi) ^ (llo & 7)) << 3));
    }
    // ---- P phase f0 ----
    {
      #pragma unroll
      for (int jn = 0; jn < 4; ++jn)
        #pragma unroll
        for (int r = 0; r < 4; ++r) {
          int row = lhi * 4 + r, col = jn * 16 + llo;
          Ps[wave][row * 64 + (col ^ ((row & 7) << 3))] = __float2bfloat16(s0[jn][r]);
        }
      bf16x8 ap0 = *reinterpret_cast<const bf16x8*>(
          &Ps[wave][llo * 64 + ((lhi ^ (llo & 7)) << 3)]);
      bf16x8 ap1 = *reinterpret_cast<const bf16x8*>(
          &Ps[wave][llo * 64 + (((4 + lhi) ^ (llo & 7)) << 3)]);
      __builtin_amdgcn_s_setprio(1);
      #pragma unroll
      for (int jd = 0; jd < 4; ++jd) {
        o0[jd] = __builtin_amdgcn_mfma_f32_16x16x32_bf16(ap0, vb0[jd], o0[jd], 0, 0, 0);
        o0[jd] = __builtin_amdgcn_mfma_f32_16x16x32_bf16(ap1, vb1[jd], o0[jd], 0, 0, 0);
      }
      __builtin_amdgcn_s_setprio(0);
    }
    // ---- P phase f1 (guarded) ----
    if (act1) {
      #pragma unroll
      for (int jn = 0; jn < 4; ++jn)
        #pragma unroll
        for (int r = 0; r < 4; ++r) {
          int row = lhi * 4 + r, col = jn * 16 + llo;
          Ps[wave][row * 64 + (col ^ ((row & 7) << 3))] = __float2bfloat16(s1[jn][r]);
        }
      bf16x8 ap0 = *reinterpret_cast<const bf16x8*>(
          &Ps[wave][llo * 64 + ((lhi ^ (llo & 7)) << 3)]);
      bf16x8 ap1 = *reinterpret_cast<const bf16x8*>(
          &Ps[wave][llo * 64 + (((4 + lhi) ^ (llo & 7)) << 3)]);
      __builtin_amdgcn_s_setprio(1);
      #pragma unroll
      for (int jd = 0; jd < 4; ++jd) {
        o1[jd] = __builtin_amdgcn_mfma_f32_16x16x32_bf16(ap0, vb0[jd], o1[jd], 0, 0, 0);
        o1[jd] = __builtin_amdgcn_mfma_f32_16x16x32_bf16(ap1, vb1[jd], o1[jd], 0, 0, 0);
      }
      __builtin_amdgcn_s_setprio(0);
    }
  }

  // final row-sum reduce across the 16-lane group, then normalize + store
  const int b = bh >> 4, h = bh & 15;
  float lr0[4], lr1[4];
  #pragma unroll
  for (int r = 0; r < 4; ++r) {
    float ps = l0[r];
    #pragma unroll
    for (int d = 1; d < 16; d <<= 1) ps += __shfl_xor(ps, d);
    lr0[r] = ps;
    float qs = l1[r];
    #pragma unroll
    for (int d = 1; d < 16; d <<= 1) qs += __shfl_xor(qs, d);
    lr1[r] = qs;
  }
  #pragma unroll
  for (int jd = 0; jd < 4; ++jd)
    #pragma unroll
    for (int r = 0; r < 4; ++r) {
      int col = h * 64 + jd * 16 + llo;
      int t0r = qb0 + lhi * 4 + r;
      Y[((size_t)(b * T_ + t0r)) * DM_ + col] = __float2bfloat16(o0[jd][r] / lr0[r]);
      int t1r = qb1 + lhi * 4 + r;
      Y[((size_t)(b * T_ + t1r)) * DM_ + col] = __float2bfloat16(o1[jd][r] / lr1[r]);
    }
}

// ---------------- launch ----------------
extern "C" void kernel_launch(void* const* d_in, const int* in_sizes, int n_in,
                              void* d_out, int out_size, void* d_ws, size_t ws_size,
                              hipStream_t stream) {
  const float* x     = (const float*)d_in[0];
  const float* w_qkv = (const float*)d_in[1];
  const float* w_out = (const float*)d_in[2];
  float* out = (float*)d_out;
  char* ws = (char*)d_ws;

  size_t off = 0;
  __hip_bfloat16* xb    = (__hip_bfloat16*)(ws + off); off += (size_t)M_ * DM_ * 2;      // 8 MiB
  __hip_bfloat16* wqkvT = (__hip_bfloat16*)(ws + off); off += (size_t)3 * DM_ * DM_ * 2; // 6 MiB
  __hip_bfloat16* woutT = (__hip_bfloat16*)(ws + off); off += (size_t)DM_ * DM_ * 2;     // 2 MiB
  __hip_bfloat16* q_ws  = (__hip_bfloat16*)(ws + off); off += (size_t)M_ * DM_ * 2;      // 8 MiB
  __hip_bfloat16* k_ws  = (__hip_bfloat16*)(ws + off); off += (size_t)M_ * DM_ * 2;      // 8 MiB
  __hip_bfloat16* vT    = (__hip_bfloat16*)(ws + off); off += (size_t)M_ * DM_ * 2;      // 8 MiB
  __hip_bfloat16* y_ws  = (__hip_bfloat16*)(ws + off); off += (size_t)M_ * DM_ * 2;      // 8 MiB
  (void)ws_size; (void)in_sizes; (void)n_in; (void)out_size;

  // fused prep: cvt x + transpose both weights (one launch)
  k_prep<<<8192, 256, 0, stream>>>(x, w_qkv, w_out, xb, wqkvT, woutT);

  // qkv projection (Q pre-scaled; V written directly transposed)
  k_gemm_qkv<<<dim3(3 * DM_ / 128, M_ / 128), 256, 0, stream>>>(xb, wqkvT, q_ws, k_ws, vT);

  // causal flash attention (v10: QBLK=32/wave on v6 skeleton)
  k_attn<<<dim3(8, BH_), 512, 0, stream>>>(q_ws, k_ws, vT, y_ws);

  // output projection (f32 out), 128x64 tiles -> 512 blocks
  k_gemm_out<<<dim3(DM_ / 64, M_ / 128), 256, 0, stream>>>(y_ws, woutT, out);
}

// Round 13
// 100.917 us; speedup vs baseline: 1.0721x; 1.0721x over previous
//
#include <hip/hip_runtime.h>
#include <hip/hip_bf16.h>
#include <stdint.h>

typedef __bf16 bf16x8 __attribute__((ext_vector_type(8)));
typedef float  f32x4  __attribute__((ext_vector_type(4)));

#define B_   2
#define T_   2048
#define H_   16
#define DH_  64
#define DM_  1024
#define BH_  (B_*H_)   // 32
#define M_   (B_*T_)   // 4096

#define QSCALE 0.18033688f   // 1/sqrt(64) * log2(e), folded into Q
#define FIXED_M 8.0f         // static softmax max (exp2 domain)

// ---- async global->LDS, 16B per lane; LDS dest must be wave-uniform base ----
static __device__ __forceinline__ void gload_lds16(const void* g, void* lds) {
  __builtin_amdgcn_global_load_lds(
      (const __attribute__((address_space(1))) void*)(uintptr_t)g,
      (__attribute__((address_space(3))) void*)(uint32_t)(uintptr_t)lds,
      16, 0, 0);
}

// ---------------- fused prep: cvt x + transpose both weights ----------------
__global__ void k_prep(const float* __restrict__ x, const float* __restrict__ wqkv,
                       const float* __restrict__ wout, __hip_bfloat16* __restrict__ xb,
                       __hip_bfloat16* __restrict__ wqkvT, __hip_bfloat16* __restrict__ woutT) {
  __shared__ float tile[32][33];
  const int bid = blockIdx.x, tid = threadIdx.x;
  if (bid < 4096) {
    int i = bid * 256 + tid;                       // 1M float4 = all of x
    float4 v = reinterpret_cast<const float4*>(x)[i];
    alignas(8) __hip_bfloat16 t[4] = {__float2bfloat16(v.x), __float2bfloat16(v.y),
                                      __float2bfloat16(v.z), __float2bfloat16(v.w)};
    reinterpret_cast<uint2*>(xb)[i] = *reinterpret_cast<const uint2*>(t);
    return;
  }
  const float* in; __hip_bfloat16* out; int K, N, n0, k0;
  if (bid < 7168) {
    int t = bid - 4096; in = wqkv; out = wqkvT; K = 1024; N = 3072;
    n0 = (t % 96) * 32; k0 = (t / 96) * 32;
  } else {
    int t = bid - 7168; in = wout; out = woutT; K = 1024; N = 1024;
    n0 = (t % 32) * 32; k0 = (t / 32) * 32;
  }
  int kl = tid >> 3, n4 = (tid & 7) * 4;
  float4 v = *reinterpret_cast<const float4*>(in + (size_t)(k0 + kl) * N + n0 + n4);
  tile[kl][n4 + 0] = v.x; tile[kl][n4 + 1] = v.y; tile[kl][n4 + 2] = v.z; tile[kl][n4 + 3] = v.w;
  __syncthreads();
  int nl = tid >> 3, k4 = (tid & 7) * 4;
  alignas(8) __hip_bfloat16 t[4];
  #pragma unroll
  for (int j = 0; j < 4; ++j) t[j] = __float2bfloat16(tile[k4 + j][nl]);
  *reinterpret_cast<uint2*>(out + (size_t)(n0 + nl) * K + k0 + k4) = *reinterpret_cast<const uint2*>(t);
}

// ---- pipelined bf16 GEMM core (B^T input), BK=32, 4 waves, 3-slot ring ----
template<int BM, int BN, int FM, int FN>
static __device__ __forceinline__ void gemm_core_pipe(
    const __hip_bfloat16* __restrict__ A, const __hip_bfloat16* __restrict__ BT,
    int K, int brow, int bcol, __hip_bfloat16* As, __hip_bfloat16* Bs,
    f32x4 acc[FM][FN]) {
  constexpr int WGN = BN / (16 * FN);
  constexpr int LOADS = BM / 64 + BN / 64;       // gloads per wave per stage
  constexpr int ASLOT = BM * 32, BSLOT = BN * 32;
  const int tid = threadIdx.x, wave = tid >> 6, lane = tid & 63;
  const int wr = wave / WGN, wc = wave % WGN;
  const int llo = lane & 15, lhi = lane >> 4;
  const int nk = K / 32;
  auto stage = [&](int ks, int slot) {
    #pragma unroll
    for (int c = wave; c < BM / 16; c += 4)
      gload_lds16(A + (size_t)(brow + c * 16 + (lane >> 2)) * K + ks * 32 + (lane & 3) * 8,
                  As + slot * ASLOT + c * 512);
    #pragma unroll
    for (int c = wave; c < BN / 16; c += 4)
      gload_lds16(BT + (size_t)(bcol + c * 16 + (lane >> 2)) * K + ks * 32 + (lane & 3) * 8,
                  Bs + slot * BSLOT + c * 512);
  };
  stage(0, 0);
  stage(1, 1);
  for (int ks = 0; ks < nk; ++ks) {
    if constexpr (LOADS == 4)      asm volatile("s_waitcnt vmcnt(4)" ::: "memory");
    else if constexpr (LOADS == 3) asm volatile("s_waitcnt vmcnt(3)" ::: "memory");
    else                           asm volatile("s_waitcnt vmcnt(0)" ::: "memory");
    __builtin_amdgcn_sched_barrier(0);
    __builtin_amdgcn_s_barrier();
    __builtin_amdgcn_sched_barrier(0);
    const int s2 = (ks + 2 < nk) ? ks + 2 : nk - 1;  // clamped redundant tail
    stage(s2, (ks + 2) % 3);
    const __hip_bfloat16* Asl = As + (ks % 3) * ASLOT;
    const __hip_bfloat16* Bsl = Bs + (ks % 3) * BSLOT;
    bf16x8 a[FM], b[FN];
    #pragma unroll
    for (int i = 0; i < FM; ++i)
      a[i] = *reinterpret_cast<const bf16x8*>(Asl + (wr * FM * 16 + i * 16 + llo) * 32 + lhi * 8);
    #pragma unroll
    for (int j = 0; j < FN; ++j)
      b[j] = *reinterpret_cast<const bf16x8*>(Bsl + (wc * FN * 16 + j * 16 + llo) * 32 + lhi * 8);
    __builtin_amdgcn_s_setprio(1);
    #pragma unroll
    for (int i = 0; i < FM; ++i)
      #pragma unroll
      for (int j = 0; j < FN; ++j)
        acc[i][j] = __builtin_amdgcn_mfma_f32_16x16x32_bf16(a[i], b[j], acc[i][j], 0, 0, 0);
    __builtin_amdgcn_s_setprio(0);
  }
  asm volatile("s_waitcnt vmcnt(0)" ::: "memory");
}

// GEMM1: qkv = xb @ w_qkv ; Q (pre-scaled) / K as [bh][t][dh]; V directly
// transposed to [bh][dh][t] (4 consecutive t per lane -> packed 8B store).
__global__ __launch_bounds__(256) void k_gemm_qkv(
    const __hip_bfloat16* __restrict__ A, const __hip_bfloat16* __restrict__ BT,
    __hip_bfloat16* __restrict__ q_ws, __hip_bfloat16* __restrict__ k_ws,
    __hip_bfloat16* __restrict__ vT) {
  alignas(16) __shared__ __hip_bfloat16 As[3 * 128 * 32];
  alignas(16) __shared__ __hip_bfloat16 Bs[3 * 128 * 32];
  f32x4 acc[4][4] = {};
  const int brow = blockIdx.y * 128, bcol = blockIdx.x * 128;
  gemm_core_pipe<128, 128, 4, 4>(A, BT, DM_, brow, bcol, As, Bs, acc);
  const int tid = threadIdx.x, wave = tid >> 6, lane = tid & 63;
  const int wr = wave >> 1, wc = wave & 1;
  const int llo = lane & 15, lhi = lane >> 4;
  #pragma unroll
  for (int i = 0; i < 4; ++i) {
    const int tbase = brow + wr * 64 + i * 16 + lhi * 4;  // 4 consecutive t
    const int b = tbase >> 11, t = tbase & 2047;
    #pragma unroll
    for (int j = 0; j < 4; ++j) {
      int n = bcol + wc * 64 + j * 16 + llo;
      int part = n >> 10, rem = n & 1023, hh = rem >> 6, dh = rem & 63;
      if (part == 2) {
        alignas(8) __hip_bfloat16 tv[4];
        #pragma unroll
        for (int r = 0; r < 4; ++r) tv[r] = __float2bfloat16(acc[i][j][r]);
        *reinterpret_cast<uint2*>(
            vT + (((size_t)(b * H_ + hh)) * DH_ + dh) * T_ + t) =
            *reinterpret_cast<const uint2*>(tv);
      } else {
        float sc = (part == 0) ? QSCALE : 1.0f;   // fold softmax scale into Q
        __hip_bfloat16* dst = (part == 0) ? q_ws : k_ws;
        #pragma unroll
        for (int r = 0; r < 4; ++r)
          dst[(((size_t)(b * H_ + hh)) * T_ + t + r) * DH_ + dh] =
              __float2bfloat16(acc[i][j][r] * sc);
      }
    }
  }
}

// GEMM2: out = y @ w_out (f32 output). 128x64 tile -> 512 blocks (2/CU).
__global__ __launch_bounds__(256) void k_gemm_out(
    const __hip_bfloat16* __restrict__ A, const __hip_bfloat16* __restrict__ BT,
    float* __restrict__ C) {
  alignas(16) __shared__ __hip_bfloat16 As[3 * 128 * 32];
  alignas(16) __shared__ __hip_bfloat16 Bs[3 * 64 * 32];
  f32x4 acc[4][2] = {};
  const int brow = blockIdx.y * 128, bcol = blockIdx.x * 64;
  gemm_core_pipe<128, 64, 4, 2>(A, BT, DM_, brow, bcol, As, Bs, acc);
  const int tid = threadIdx.x, wave = tid >> 6, lane = tid & 63;
  const int wr = wave >> 1, wc = wave & 1;
  const int llo = lane & 15, lhi = lane >> 4;
  #pragma unroll
  for (int i = 0; i < 4; ++i)
    #pragma unroll
    for (int j = 0; j < 2; ++j) {
      int n = bcol + wc * 32 + j * 16 + llo;
      #pragma unroll
      for (int r = 0; r < 4; ++r) {
        int m = brow + wr * 64 + i * 16 + lhi * 4 + r;
        C[(size_t)m * DM_ + n] = acc[i][j][r];
      }
    }
}

// ---------------- flash attention (causal), v12 ----------------
// v6 skeleton verbatim + swapped-operand MFMAs (S^T = mfma(K,Q), O^T =
// mfma(V,P)): lane holds q = llo fixed, 4 consecutive t' per (jn) -> P-pack
// becomes 4x 8B ds_write (vs 16 scalar) and row-sum is lane-local.
// vs round-12 failure: (1) pack via __float2bfloat16 array + uint2 (proven
// idiom, no inline-asm cvt_pk); (2) explicit compiler memory fence between
// P writes (uint2-typed) and P reads (bf16x8-typed) — TBAA treats them as
// no-alias and may otherwise hoist the ds_read above the writes.
__global__ __launch_bounds__(512) void k_attn(
    const __hip_bfloat16* __restrict__ Q, const __hip_bfloat16* __restrict__ Kk,
    const __hip_bfloat16* __restrict__ VT, __hip_bfloat16* __restrict__ Y) {
  alignas(16) __shared__ __hip_bfloat16 Ks[4][64 * 64];
  alignas(16) __shared__ __hip_bfloat16 Vs[4][64 * 64];   // [dh][t'] swizzled
  alignas(16) __shared__ __hip_bfloat16 Ps[8][16 * 64];
  const int bh = blockIdx.y;
  const int p  = blockIdx.x;                 // 0..15
  const int tid = threadIdx.x, wave = tid >> 6, lane = tid & 63;
  const int llo = lane & 15, lhi = lane >> 4;
  const int qt   = (wave < 4) ? (31 - p) : p;
  const int myNt = qt + 1;
  const int ntA  = 32 - p;                   // block loop length (>= 17)
  const int q0 = qt * 64;
  const int qbase = q0 + (wave & 3) * 16;
  const int myq = qbase + llo;               // this lane's q row (swapped layout)

  const __hip_bfloat16* kb = Kk + (size_t)bh * T_ * DH_;
  const __hip_bfloat16* vb = VT + (size_t)bh * DH_ * T_;

  const int srow = lane >> 3;                // 0..7
  const int schunk = (lane & 7) ^ srow;      // involution XOR
  const int rb = wave * 8;

  bf16x8 aq[2];
  #pragma unroll
  for (int k0 = 0; k0 < 2; ++k0)
    aq[k0] = *reinterpret_cast<const bf16x8*>(
        Q + ((size_t)bh * T_ + myq) * DH_ + k0 * 32 + lhi * 8);

  float lsum = 0.f;                          // scalar row-sum (q = myq)
  f32x4 o[4] = {};

  // prologue: stage tiles 0,1 into buffers 0,1 (ntA >= 17 so both exist)
  gload_lds16(kb + (size_t)(rb + srow) * DH_ + schunk * 8, &Ks[0][rb * 64]);
  gload_lds16(vb + (size_t)(rb + srow) * T_ + schunk * 8, &Vs[0][rb * 64]);
  gload_lds16(kb + (size_t)(64 + rb + srow) * DH_ + schunk * 8, &Ks[1][rb * 64]);
  gload_lds16(vb + (size_t)(rb + srow) * T_ + 64 + schunk * 8, &Vs[1][rb * 64]);

  char* psw = reinterpret_cast<char*>(&Ps[wave][0]);

  for (int it = 0; it < ntA; ++it) {
    const int cur = it & 3;
    // stage tile it+2 (clamped tail keeps 2 loads/wave/iter: vmcnt(4) exact)
    {
      const int ts = (it + 2 < ntA) ? (it + 2) : (ntA - 1);
      const int bs = (it + 2) & 3;
      const int tn = ts * 64;
      gload_lds16(kb + (size_t)(tn + rb + srow) * DH_ + schunk * 8, &Ks[bs][rb * 64]);
      gload_lds16(vb + (size_t)(rb + srow) * T_ + tn + schunk * 8, &Vs[bs][rb * 64]);
    }
    asm volatile("s_waitcnt vmcnt(4)" ::: "memory");
    __builtin_amdgcn_sched_barrier(0);
    __builtin_amdgcn_s_barrier();
    __builtin_amdgcn_sched_barrier(0);

    if (it < myNt) {    // wave-uniform guard (waves 4-7 finish early)
      const __hip_bfloat16* ksb = Ks[cur];
      const __hip_bfloat16* vsb = Vs[cur];

      // S^T = K Q^T (swapped operands; addresses identical to v6)
      f32x4 s[4];
      __builtin_amdgcn_s_setprio(1);
      #pragma unroll
      for (int jn = 0; jn < 4; ++jn) {
        const __hip_bfloat16* krow = ksb + (jn * 16 + llo) * 64;
        bf16x8 b0 = *reinterpret_cast<const bf16x8*>(krow + ((lhi ^ (llo & 7)) << 3));
        bf16x8 b1 = *reinterpret_cast<const bf16x8*>(krow + (((4 + lhi) ^ (llo & 7)) << 3));
        f32x4 z = {};
        z = __builtin_amdgcn_mfma_f32_16x16x32_bf16(b0, aq[0], z, 0, 0, 0);
        z = __builtin_amdgcn_mfma_f32_16x16x32_bf16(b1, aq[1], z, 0, 0, 0);
        s[jn] = z;   // s[jn][r] = S[t' = it*64 + jn*16 + lhi*4 + r][q = myq]
      }
      __builtin_amdgcn_s_setprio(0);
      // causal mask only on the diagonal tile: t' > q -> -inf
      if (it == myNt - 1) {
        #pragma unroll
        for (int jn = 0; jn < 4; ++jn)
          #pragma unroll
          for (int r = 0; r < 4; ++r) {
            int tprime = q0 + jn * 16 + lhi * 4 + r;
            if (tprime > myq) s[jn][r] = -INFINITY;
          }
      }
      // static-max softmax + pack: 4 consecutive t' per (jn) -> one 8B write
      #pragma unroll
      for (int jn = 0; jn < 4; ++jn) {
        float p0 = __builtin_amdgcn_exp2f(s[jn][0] - FIXED_M);
        float p1 = __builtin_amdgcn_exp2f(s[jn][1] - FIXED_M);
        float p2 = __builtin_amdgcn_exp2f(s[jn][2] - FIXED_M);
        float p3 = __builtin_amdgcn_exp2f(s[jn][3] - FIXED_M);
        lsum += (p0 + p1) + (p2 + p3);
        alignas(8) __hip_bfloat16 hp[4] = {
            __float2bfloat16(p0), __float2bfloat16(p1),
            __float2bfloat16(p2), __float2bfloat16(p3)};
        // logical 16B chunk = jn*2 + (lhi>>1), swizzled ^(llo&7); 8B half = lhi&1
        int wbyte = llo * 128 + ((((jn << 1) | (lhi >> 1)) ^ (llo & 7)) << 4) + ((lhi & 1) << 3);
        *reinterpret_cast<uint2*>(psw + wbyte) = *reinterpret_cast<const uint2*>(hp);
      }
      // compiler fence: uint2 stores vs bf16x8 loads are TBAA-distinct; do
      // not let the P fragment reads get hoisted above the pack writes.
      asm volatile("" ::: "memory");
      // PV: O^T = mfma(A = V^T-frag, B = P-frag); addresses identical to v6
      bf16x8 ap0 = *reinterpret_cast<const bf16x8*>(
          &Ps[wave][llo * 64 + ((lhi ^ (llo & 7)) << 3)]);
      bf16x8 ap1 = *reinterpret_cast<const bf16x8*>(
          &Ps[wave][llo * 64 + (((4 + lhi) ^ (llo & 7)) << 3)]);
      __builtin_amdgcn_s_setprio(1);
      #pragma unroll
      for (int jd = 0; jd < 4; ++jd) {
        const __hip_bfloat16* vrow = vsb + (jd * 16 + llo) * 64;
        bf16x8 v0 = *reinterpret_cast<const bf16x8*>(vrow + ((lhi ^ (llo & 7)) << 3));
        bf16x8 v1 = *reinterpret_cast<const bf16x8*>(vrow + (((4 + lhi) ^ (llo & 7)) << 3));
        o[jd] = __builtin_amdgcn_mfma_f32_16x16x32_bf16(v0, ap0, o[jd], 0, 0, 0);
        o[jd] = __builtin_amdgcn_mfma_f32_16x16x32_bf16(v1, ap1, o[jd], 0, 0, 0);
      }
      __builtin_amdgcn_s_setprio(0);
    }
  }

  // row-sum: lanes {llo, llo+16, llo+32, llo+48} hold partials for q = myq
  lsum += __shfl_xor(lsum, 16);
  lsum += __shfl_xor(lsum, 32);
  const float inv = 1.0f / lsum;

  // epilogue: o[jd][r] = O[q = myq][dh = jd*16 + lhi*4 + r]; packed 8B stores
  const int b = bh >> 4, h = bh & 15;
  __hip_bfloat16* yrow = Y + ((size_t)(b * T_ + myq)) * DM_ + h * 64;
  #pragma unroll
  for (int jd = 0; jd < 4; ++jd) {
    alignas(8) __hip_bfloat16 t4[4];
    #pragma unroll
    for (int r = 0; r < 4; ++r) t4[r] = __float2bfloat16(o[jd][r] * inv);
    *reinterpret_cast<uint2*>(yrow + jd * 16 + lhi * 4) =
        *reinterpret_cast<const uint2*>(t4);
  }
}

// ---------------- launch ----------------
extern "C" void kernel_launch(void* const* d_in, const int* in_sizes, int n_in,
                              void* d_out, int out_size, void* d_ws, size_t ws_size,
                              hipStream_t stream) {
  const float* x     = (const float*)d_in[0];
  const float* w_qkv = (const float*)d_in[1];
  const float* w_out = (const float*)d_in[2];
  float* out = (float*)d_out;
  char* ws = (char*)d_ws;

  size_t off = 0;
  __hip_bfloat16* xb    = (__hip_bfloat16*)(ws + off); off += (size_t)M_ * DM_ * 2;      // 8 MiB
  __hip_bfloat16* wqkvT = (__hip_bfloat16*)(ws + off); off += (size_t)3 * DM_ * DM_ * 2; // 6 MiB
  __hip_bfloat16* woutT = (__hip_bfloat16*)(ws + off); off += (size_t)DM_ * DM_ * 2;     // 2 MiB
  __hip_bfloat16* q_ws  = (__hip_bfloat16*)(ws + off); off += (size_t)M_ * DM_ * 2;      // 8 MiB
  __hip_bfloat16* k_ws  = (__hip_bfloat16*)(ws + off); off += (size_t)M_ * DM_ * 2;      // 8 MiB
  __hip_bfloat16* vT    = (__hip_bfloat16*)(ws + off); off += (size_t)M_ * DM_ * 2;      // 8 MiB
  __hip_bfloat16* y_ws  = (__hip_bfloat16*)(ws + off); off += (size_t)M_ * DM_ * 2;      // 8 MiB
  (void)ws_size; (void)in_sizes; (void)n_in; (void)out_size;

  // fused prep: cvt x + transpose both weights (one launch)
  k_prep<<<8192, 256, 0, stream>>>(x, w_qkv, w_out, xb, wqkvT, woutT);

  // qkv projection (Q pre-scaled; V written directly transposed)
  k_gemm_qkv<<<dim3(3 * DM_ / 128, M_ / 128), 256, 0, stream>>>(xb, wqkvT, q_ws, k_ws, vT);

  // causal flash attention (v12: v6 skeleton + swapped-operand MFMA, fixed)
  k_attn<<<dim3(T_ / 128, BH_), 512, 0, stream>>>(q_ws, k_ws, vT, y_ws);

  // output projection (f32 out), 128x64 tiles -> 512 blocks
  k_gemm_out<<<dim3(DM_ / 64, M_ / 128), 256, 0, stream>>>(y_ws, woutT, out);
}

// Round 14
// 99.882 us; speedup vs baseline: 1.0832x; 1.0104x over previous
//
#include <hip/hip_runtime.h>
#include <hip/hip_bf16.h>
#include <stdint.h>

typedef __bf16 bf16x8 __attribute__((ext_vector_type(8)));
typedef float  f32x4  __attribute__((ext_vector_type(4)));

#define B_   2
#define T_   2048
#define H_   16
#define DH_  64
#define DM_  1024
#define BH_  (B_*H_)   // 32
#define M_   (B_*T_)   // 4096

#define QSCALE 0.18033688f   // 1/sqrt(64) * log2(e), folded into Q
#define FIXED_M 8.0f         // static softmax max (exp2 domain)

// ---- async global->LDS, 16B per lane; LDS dest must be wave-uniform base ----
static __device__ __forceinline__ void gload_lds16(const void* g, void* lds) {
  __builtin_amdgcn_global_load_lds(
      (const __attribute__((address_space(1))) void*)(uintptr_t)g,
      (__attribute__((address_space(3))) void*)(uint32_t)(uintptr_t)lds,
      16, 0, 0);
}

// ---------------- fused prep: cvt x + transpose both weights ----------------
__global__ void k_prep(const float* __restrict__ x, const float* __restrict__ wqkv,
                       const float* __restrict__ wout, __hip_bfloat16* __restrict__ xb,
                       __hip_bfloat16* __restrict__ wqkvT, __hip_bfloat16* __restrict__ woutT) {
  __shared__ float tile[32][33];
  const int bid = blockIdx.x, tid = threadIdx.x;
  if (bid < 4096) {
    int i = bid * 256 + tid;                       // 1M float4 = all of x
    float4 v = reinterpret_cast<const float4*>(x)[i];
    alignas(8) __hip_bfloat16 t[4] = {__float2bfloat16(v.x), __float2bfloat16(v.y),
                                      __float2bfloat16(v.z), __float2bfloat16(v.w)};
    reinterpret_cast<uint2*>(xb)[i] = *reinterpret_cast<const uint2*>(t);
    return;
  }
  const float* in; __hip_bfloat16* out; int K, N, n0, k0;
  if (bid < 7168) {
    int t = bid - 4096; in = wqkv; out = wqkvT; K = 1024; N = 3072;
    n0 = (t % 96) * 32; k0 = (t / 96) * 32;
  } else {
    int t = bid - 7168; in = wout; out = woutT; K = 1024; N = 1024;
    n0 = (t % 32) * 32; k0 = (t / 32) * 32;
  }
  int kl = tid >> 3, n4 = (tid & 7) * 4;
  float4 v = *reinterpret_cast<const float4*>(in + (size_t)(k0 + kl) * N + n0 + n4);
  tile[kl][n4 + 0] = v.x; tile[kl][n4 + 1] = v.y; tile[kl][n4 + 2] = v.z; tile[kl][n4 + 3] = v.w;
  __syncthreads();
  int nl = tid >> 3, k4 = (tid & 7) * 4;
  alignas(8) __hip_bfloat16 t[4];
  #pragma unroll
  for (int j = 0; j < 4; ++j) t[j] = __float2bfloat16(tile[k4 + j][nl]);
  *reinterpret_cast<uint2*>(out + (size_t)(n0 + nl) * K + k0 + k4) = *reinterpret_cast<const uint2*>(t);
}

// ---- pipelined bf16 GEMM core (B^T input), BK=32, 4 waves, 3-slot ring ----
// LDS XOR-swizzle (G21 both-sides): stage reads global 16B chunk
// (lane&3)^((lane>>3)&3) into linear LDS; fragment read uses chunkpos =
// lhi ^ ((llo>>1)&3). 16 lanes -> banks {0,4,...,28} x2 = 2-way (free),
// vs 8-way before (3.1e6 conflict cycles in k_gemm_qkv).
template<int BM, int BN, int FM, int FN>
static __device__ __forceinline__ void gemm_core_pipe(
    const __hip_bfloat16* __restrict__ A, const __hip_bfloat16* __restrict__ BT,
    int K, int brow, int bcol, __hip_bfloat16* As, __hip_bfloat16* Bs,
    f32x4 acc[FM][FN]) {
  constexpr int WGN = BN / (16 * FN);
  constexpr int LOADS = BM / 64 + BN / 64;       // gloads per wave per stage
  constexpr int ASLOT = BM * 32, BSLOT = BN * 32;
  const int tid = threadIdx.x, wave = tid >> 6, lane = tid & 63;
  const int wr = wave / WGN, wc = wave % WGN;
  const int llo = lane & 15, lhi = lane >> 4;
  const int nk = K / 32;
  // pre-swizzled global chunk: row-within-subtile = lane>>2, chunk = lane&3
  const int schunk = (lane & 3) ^ ((lane >> 3) & 3);
  auto stage = [&](int ks, int slot) {
    #pragma unroll
    for (int c = wave; c < BM / 16; c += 4)
      gload_lds16(A + (size_t)(brow + c * 16 + (lane >> 2)) * K + ks * 32 + schunk * 8,
                  As + slot * ASLOT + c * 512);
    #pragma unroll
    for (int c = wave; c < BN / 16; c += 4)
      gload_lds16(BT + (size_t)(bcol + c * 16 + (lane >> 2)) * K + ks * 32 + schunk * 8,
                  Bs + slot * BSLOT + c * 512);
  };
  stage(0, 0);
  stage(1, 1);
  const int rchunk = lhi ^ ((llo >> 1) & 3);     // swizzled read chunk
  for (int ks = 0; ks < nk; ++ks) {
    if constexpr (LOADS == 4)      asm volatile("s_waitcnt vmcnt(4)" ::: "memory");
    else if constexpr (LOADS == 3) asm volatile("s_waitcnt vmcnt(3)" ::: "memory");
    else                           asm volatile("s_waitcnt vmcnt(0)" ::: "memory");
    __builtin_amdgcn_sched_barrier(0);
    __builtin_amdgcn_s_barrier();
    __builtin_amdgcn_sched_barrier(0);
    const int s2 = (ks + 2 < nk) ? ks + 2 : nk - 1;  // clamped redundant tail
    stage(s2, (ks + 2) % 3);
    const __hip_bfloat16* Asl = As + (ks % 3) * ASLOT;
    const __hip_bfloat16* Bsl = Bs + (ks % 3) * BSLOT;
    bf16x8 a[FM], b[FN];
    #pragma unroll
    for (int i = 0; i < FM; ++i)
      a[i] = *reinterpret_cast<const bf16x8*>(
          Asl + (wr * FM * 16 + i * 16 + llo) * 32 + rchunk * 8);
    #pragma unroll
    for (int j = 0; j < FN; ++j)
      b[j] = *reinterpret_cast<const bf16x8*>(
          Bsl + (wc * FN * 16 + j * 16 + llo) * 32 + rchunk * 8);
    __builtin_amdgcn_s_setprio(1);
    #pragma unroll
    for (int i = 0; i < FM; ++i)
      #pragma unroll
      for (int j = 0; j < FN; ++j)
        acc[i][j] = __builtin_amdgcn_mfma_f32_16x16x32_bf16(a[i], b[j], acc[i][j], 0, 0, 0);
    __builtin_amdgcn_s_setprio(0);
  }
  asm volatile("s_waitcnt vmcnt(0)" ::: "memory");
}

// GEMM1: qkv = xb @ w_qkv ; Q (pre-scaled) / K as [bh][t][dh]; V directly
// transposed to [bh][dh][t] (4 consecutive t per lane -> packed 8B store).
__global__ __launch_bounds__(256) void k_gemm_qkv(
    const __hip_bfloat16* __restrict__ A, const __hip_bfloat16* __restrict__ BT,
    __hip_bfloat16* __restrict__ q_ws, __hip_bfloat16* __restrict__ k_ws,
    __hip_bfloat16* __restrict__ vT) {
  alignas(16) __shared__ __hip_bfloat16 As[3 * 128 * 32];
  alignas(16) __shared__ __hip_bfloat16 Bs[3 * 128 * 32];
  f32x4 acc[4][4] = {};
  const int brow = blockIdx.y * 128, bcol = blockIdx.x * 128;
  gemm_core_pipe<128, 128, 4, 4>(A, BT, DM_, brow, bcol, As, Bs, acc);
  const int tid = threadIdx.x, wave = tid >> 6, lane = tid & 63;
  const int wr = wave >> 1, wc = wave & 1;
  const int llo = lane & 15, lhi = lane >> 4;
  #pragma unroll
  for (int i = 0; i < 4; ++i) {
    const int tbase = brow + wr * 64 + i * 16 + lhi * 4;  // 4 consecutive t
    const int b = tbase >> 11, t = tbase & 2047;
    #pragma unroll
    for (int j = 0; j < 4; ++j) {
      int n = bcol + wc * 64 + j * 16 + llo;
      int part = n >> 10, rem = n & 1023, hh = rem >> 6, dh = rem & 63;
      if (part == 2) {
        alignas(8) __hip_bfloat16 tv[4];
        #pragma unroll
        for (int r = 0; r < 4; ++r) tv[r] = __float2bfloat16(acc[i][j][r]);
        *reinterpret_cast<uint2*>(
            vT + (((size_t)(b * H_ + hh)) * DH_ + dh) * T_ + t) =
            *reinterpret_cast<const uint2*>(tv);
      } else {
        float sc = (part == 0) ? QSCALE : 1.0f;   // fold softmax scale into Q
        __hip_bfloat16* dst = (part == 0) ? q_ws : k_ws;
        #pragma unroll
        for (int r = 0; r < 4; ++r)
          dst[(((size_t)(b * H_ + hh)) * T_ + t + r) * DH_ + dh] =
              __float2bfloat16(acc[i][j][r] * sc);
      }
    }
  }
}

// GEMM2: out = y @ w_out (f32 output). 128x64 tile -> 512 blocks (2/CU).
__global__ __launch_bounds__(256) void k_gemm_out(
    const __hip_bfloat16* __restrict__ A, const __hip_bfloat16* __restrict__ BT,
    float* __restrict__ C) {
  alignas(16) __shared__ __hip_bfloat16 As[3 * 128 * 32];
  alignas(16) __shared__ __hip_bfloat16 Bs[3 * 64 * 32];
  f32x4 acc[4][2] = {};
  const int brow = blockIdx.y * 128, bcol = blockIdx.x * 64;
  gemm_core_pipe<128, 64, 4, 2>(A, BT, DM_, brow, bcol, As, Bs, acc);
  const int tid = threadIdx.x, wave = tid >> 6, lane = tid & 63;
  const int wr = wave >> 1, wc = wave & 1;
  const int llo = lane & 15, lhi = lane >> 4;
  #pragma unroll
  for (int i = 0; i < 4; ++i)
    #pragma unroll
    for (int j = 0; j < 2; ++j) {
      int n = bcol + wc * 32 + j * 16 + llo;
      #pragma unroll
      for (int r = 0; r < 4; ++r) {
        int m = brow + wr * 64 + i * 16 + lhi * 4 + r;
        C[(size_t)m * DM_ + n] = acc[i][j][r];
      }
    }
}

// ---------------- flash attention (causal), v12 (passed: ~37 us) ----------
// v6 skeleton + swapped-operand MFMAs (S^T = mfma(K,Q), O^T = mfma(V,P)):
// lane holds q = llo fixed, 4 consecutive t' per (jn) -> P-pack is 4x 8B
// ds_write; row-sum lane-local. TBAA fence between P writes and P reads.
__global__ __launch_bounds__(512) void k_attn(
    const __hip_bfloat16* __restrict__ Q, const __hip_bfloat16* __restrict__ Kk,
    const __hip_bfloat16* __restrict__ VT, __hip_bfloat16* __restrict__ Y) {
  alignas(16) __shared__ __hip_bfloat16 Ks[4][64 * 64];
  alignas(16) __shared__ __hip_bfloat16 Vs[4][64 * 64];   // [dh][t'] swizzled
  alignas(16) __shared__ __hip_bfloat16 Ps[8][16 * 64];
  const int bh = blockIdx.y;
  const int p  = blockIdx.x;                 // 0..15
  const int tid = threadIdx.x, wave = tid >> 6, lane = tid & 63;
  const int llo = lane & 15, lhi = lane >> 4;
  const int qt   = (wave < 4) ? (31 - p) : p;
  const int myNt = qt + 1;
  const int ntA  = 32 - p;                   // block loop length (>= 17)
  const int q0 = qt * 64;
  const int qbase = q0 + (wave & 3) * 16;
  const int myq = qbase + llo;               // this lane's q row (swapped layout)

  const __hip_bfloat16* kb = Kk + (size_t)bh * T_ * DH_;
  const __hip_bfloat16* vb = VT + (size_t)bh * DH_ * T_;

  const int srow = lane >> 3;                // 0..7
  const int schunk = (lane & 7) ^ srow;      // involution XOR
  const int rb = wave * 8;

  bf16x8 aq[2];
  #pragma unroll
  for (int k0 = 0; k0 < 2; ++k0)
    aq[k0] = *reinterpret_cast<const bf16x8*>(
        Q + ((size_t)bh * T_ + myq) * DH_ + k0 * 32 + lhi * 8);

  float lsum = 0.f;                          // scalar row-sum (q = myq)
  f32x4 o[4] = {};

  // prologue: stage tiles 0,1 into buffers 0,1 (ntA >= 17 so both exist)
  gload_lds16(kb + (size_t)(rb + srow) * DH_ + schunk * 8, &Ks[0][rb * 64]);
  gload_lds16(vb + (size_t)(rb + srow) * T_ + schunk * 8, &Vs[0][rb * 64]);
  gload_lds16(kb + (size_t)(64 + rb + srow) * DH_ + schunk * 8, &Ks[1][rb * 64]);
  gload_lds16(vb + (size_t)(rb + srow) * T_ + 64 + schunk * 8, &Vs[1][rb * 64]);

  char* psw = reinterpret_cast<char*>(&Ps[wave][0]);

  for (int it = 0; it < ntA; ++it) {
    const int cur = it & 3;
    // stage tile it+2 (clamped tail keeps 2 loads/wave/iter: vmcnt(4) exact)
    {
      const int ts = (it + 2 < ntA) ? (it + 2) : (ntA - 1);
      const int bs = (it + 2) & 3;
      const int tn = ts * 64;
      gload_lds16(kb + (size_t)(tn + rb + srow) * DH_ + schunk * 8, &Ks[bs][rb * 64]);
      gload_lds16(vb + (size_t)(rb + srow) * T_ + tn + schunk * 8, &Vs[bs][rb * 64]);
    }
    asm volatile("s_waitcnt vmcnt(4)" ::: "memory");
    __builtin_amdgcn_sched_barrier(0);
    __builtin_amdgcn_s_barrier();
    __builtin_amdgcn_sched_barrier(0);

    if (it < myNt) {    // wave-uniform guard (waves 4-7 finish early)
      const __hip_bfloat16* ksb = Ks[cur];
      const __hip_bfloat16* vsb = Vs[cur];

      // S^T = K Q^T (swapped operands; addresses identical to v6)
      f32x4 s[4];
      __builtin_amdgcn_s_setprio(1);
      #pragma unroll
      for (int jn = 0; jn < 4; ++jn) {
        const __hip_bfloat16* krow = ksb + (jn * 16 + llo) * 64;
        bf16x8 b0 = *reinterpret_cast<const bf16x8*>(krow + ((lhi ^ (llo & 7)) << 3));
        bf16x8 b1 = *reinterpret_cast<const bf16x8*>(krow + (((4 + lhi) ^ (llo & 7)) << 3));
        f32x4 z = {};
        z = __builtin_amdgcn_mfma_f32_16x16x32_bf16(b0, aq[0], z, 0, 0, 0);
        z = __builtin_amdgcn_mfma_f32_16x16x32_bf16(b1, aq[1], z, 0, 0, 0);
        s[jn] = z;   // s[jn][r] = S[t' = it*64 + jn*16 + lhi*4 + r][q = myq]
      }
      __builtin_amdgcn_s_setprio(0);
      // causal mask only on the diagonal tile: t' > q -> -inf
      if (it == myNt - 1) {
        #pragma unroll
        for (int jn = 0; jn < 4; ++jn)
          #pragma unroll
          for (int r = 0; r < 4; ++r) {
            int tprime = q0 + jn * 16 + lhi * 4 + r;
            if (tprime > myq) s[jn][r] = -INFINITY;
          }
      }
      // static-max softmax + pack: 4 consecutive t' per (jn) -> one 8B write
      #pragma unroll
      for (int jn = 0; jn < 4; ++jn) {
        float p0 = __builtin_amdgcn_exp2f(s[jn][0] - FIXED_M);
        float p1 = __builtin_amdgcn_exp2f(s[jn][1] - FIXED_M);
        float p2 = __builtin_amdgcn_exp2f(s[jn][2] - FIXED_M);
        float p3 = __builtin_amdgcn_exp2f(s[jn][3] - FIXED_M);
        lsum += (p0 + p1) + (p2 + p3);
        alignas(8) __hip_bfloat16 hp[4] = {
            __float2bfloat16(p0), __float2bfloat16(p1),
            __float2bfloat16(p2), __float2bfloat16(p3)};
        // logical 16B chunk = jn*2 + (lhi>>1), swizzled ^(llo&7); 8B half = lhi&1
        int wbyte = llo * 128 + ((((jn << 1) | (lhi >> 1)) ^ (llo & 7)) << 4) + ((lhi & 1) << 3);
        *reinterpret_cast<uint2*>(psw + wbyte) = *reinterpret_cast<const uint2*>(hp);
      }
      // compiler fence: uint2 stores vs bf16x8 loads are TBAA-distinct; do
      // not let the P fragment reads get hoisted above the pack writes.
      asm volatile("" ::: "memory");
      // PV: O^T = mfma(A = V^T-frag, B = P-frag); addresses identical to v6
      bf16x8 ap0 = *reinterpret_cast<const bf16x8*>(
          &Ps[wave][llo * 64 + ((lhi ^ (llo & 7)) << 3)]);
      bf16x8 ap1 = *reinterpret_cast<const bf16x8*>(
          &Ps[wave][llo * 64 + (((4 + lhi) ^ (llo & 7)) << 3)]);
      __builtin_amdgcn_s_setprio(1);
      #pragma unroll
      for (int jd = 0; jd < 4; ++jd) {
        const __hip_bfloat16* vrow = vsb + (jd * 16 + llo) * 64;
        bf16x8 v0 = *reinterpret_cast<const bf16x8*>(vrow + ((lhi ^ (llo & 7)) << 3));
        bf16x8 v1 = *reinterpret_cast<const bf16x8*>(vrow + (((4 + lhi) ^ (llo & 7)) << 3));
        o[jd] = __builtin_amdgcn_mfma_f32_16x16x32_bf16(v0, ap0, o[jd], 0, 0, 0);
        o[jd] = __builtin_amdgcn_mfma_f32_16x16x32_bf16(v1, ap1, o[jd], 0, 0, 0);
      }
      __builtin_amdgcn_s_setprio(0);
    }
  }

  // row-sum: lanes {llo, llo+16, llo+32, llo+48} hold partials for q = myq
  lsum += __shfl_xor(lsum, 16);
  lsum += __shfl_xor(lsum, 32);
  const float inv = 1.0f / lsum;

  // epilogue: o[jd][r] = O[q = myq][dh = jd*16 + lhi*4 + r]; packed 8B stores
  const int b = bh >> 4, h = bh & 15;
  __hip_bfloat16* yrow = Y + ((size_t)(b * T_ + myq)) * DM_ + h * 64;
  #pragma unroll
  for (int jd = 0; jd < 4; ++jd) {
    alignas(8) __hip_bfloat16 t4[4];
    #pragma unroll
    for (int r = 0; r < 4; ++r) t4[r] = __float2bfloat16(o[jd][r] * inv);
    *reinterpret_cast<uint2*>(yrow + jd * 16 + lhi * 4) =
        *reinterpret_cast<const uint2*>(t4);
  }
}

// ---------------- launch ----------------
extern "C" void kernel_launch(void* const* d_in, const int* in_sizes, int n_in,
                              void* d_out, int out_size, void* d_ws, size_t ws_size,
                              hipStream_t stream) {
  const float* x     = (const float*)d_in[0];
  const float* w_qkv = (const float*)d_in[1];
  const float* w_out = (const float*)d_in[2];
  float* out = (float*)d_out;
  char* ws = (char*)d_ws;

  size_t off = 0;
  __hip_bfloat16* xb    = (__hip_bfloat16*)(ws + off); off += (size_t)M_ * DM_ * 2;      // 8 MiB
  __hip_bfloat16* wqkvT = (__hip_bfloat16*)(ws + off); off += (size_t)3 * DM_ * DM_ * 2; // 6 MiB
  __hip_bfloat16* woutT = (__hip_bfloat16*)(ws + off); off += (size_t)DM_ * DM_ * 2;     // 2 MiB
  __hip_bfloat16* q_ws  = (__hip_bfloat16*)(ws + off); off += (size_t)M_ * DM_ * 2;      // 8 MiB
  __hip_bfloat16* k_ws  = (__hip_bfloat16*)(ws + off); off += (size_t)M_ * DM_ * 2;      // 8 MiB
  __hip_bfloat16* vT    = (__hip_bfloat16*)(ws + off); off += (size_t)M_ * DM_ * 2;      // 8 MiB
  __hip_bfloat16* y_ws  = (__hip_bfloat16*)(ws + off); off += (size_t)M_ * DM_ * 2;      // 8 MiB
  (void)ws_size; (void)in_sizes; (void)n_in; (void)out_size;

  // fused prep: cvt x + transpose both weights (one launch)
  k_prep<<<8192, 256, 0, stream>>>(x, w_qkv, w_out, xb, wqkvT, woutT);

  // qkv projection (Q pre-scaled; V written directly transposed)
  k_gemm_qkv<<<dim3(3 * DM_ / 128, M_ / 128), 256, 0, stream>>>(xb, wqkvT, q_ws, k_ws, vT);

  // causal flash attention (v12: swapped-operand MFMA)
  k_attn<<<dim3(T_ / 128, BH_), 512, 0, stream>>>(q_ws, k_ws, vT, y_ws);

  // output projection (f32 out), 128x64 tiles -> 512 blocks
  k_gemm_out<<<dim3(DM_ / 64, M_ / 128), 256, 0, stream>>>(y_ws, woutT, out);
}